// Round 22
// baseline (2055.917 us; speedup 1.0000x reference)
//
#include <hip/hip_runtime.h>
#include <hip/hip_fp16.h>
#include <cstdint>
#include <cstddef>

#define T_STEPS 512
#define ROWSP   516          // padded rows per element (3-deep unconditional prefetch)
#define HID 40
#define GATES 120

typedef _Float16 half8 __attribute__((ext_vector_type(8)));
typedef _Float16 fp16x2 __attribute__((ext_vector_type(2)));
typedef float f32x4 __attribute__((ext_vector_type(4)));

__device__ __forceinline__ void wavesync() { asm volatile("s_waitcnt lgkmcnt(0)" ::: "memory"); }
__device__ __forceinline__ float bperm(int srclane, float v) {
    return __int_as_float(__builtin_amdgcn_ds_bpermute(srclane << 2, __float_as_int(v)));
}
__device__ __forceinline__ float sigm(float x) { return 1.f / (1.f + __expf(-x)); }

template<int J>
__device__ __forceinline__ fp16x2 ext2(half8 v) {
    return __builtin_shufflevector(v, v, 2 * J, 2 * J + 1);
}

#if __has_builtin(__builtin_amdgcn_fdot2)
__device__ __forceinline__ float fdot2(fp16x2 a, fp16x2 b, float c) {
    return __builtin_amdgcn_fdot2(a, b, c, false);
}
#else
__device__ __forceinline__ float fdot2(fp16x2 a, fp16x2 b, float c) {
    return c + (float)a[0] * (float)b[0] + (float)a[1] * (float)b[1];
}
#endif

// padded-row byte mapping: row i (linear e*512+t) lives at (e*516+t)*GATES
__device__ __forceinline__ size_t rowoff(int row) {
    return ((size_t)(row >> 9) * ROWSP + (row & 511)) * GATES;
}

// ---------------- weight prep (run once, tiny) ----------------
__global__ __launch_bounds__(256) void prep_pad(
    const float* __restrict__ w, const float* __restrict__ b,
    __half* __restrict__ out, int N, int K, int KPAD)
{
    const int idx = blockIdx.x * 256 + threadIdx.x;
    const int n = idx / KPAD, k = idx - n * KPAD;
    float v = 0.f;
    if (n < N) {
        if (k < K) v = w[n * K + k];
        else if (k == KPAD - 1) v = b[n];
    }
    out[idx] = __float2half(v);
}

__global__ __launch_bounds__(256) void prep_eff(
    const float* __restrict__ g_wih, const float* __restrict__ g_bih,
    const float* __restrict__ w2, const float* __restrict__ b2,
    __half* __restrict__ out)
{
    const int li  = blockIdx.y;
    const int idx = blockIdx.x * 256 + threadIdx.x;   // over 128*64
    const int n = idx >> 6, k = idx & 63;
    float v = 0.f;
    if (n < GATES) {
        const float* wrow = g_wih + ((size_t)(li + 1) * GATES + n) * HID;
        if (k < HID) {
            for (int j = 0; j < HID; ++j) v += wrow[j] * w2[((size_t)li * HID + j) * HID + k];
        } else if (k == 63) {
            v = g_bih[(size_t)(li + 1) * GATES + n];
            for (int j = 0; j < HID; ++j) v += wrow[j] * b2[(size_t)li * HID + j];
        }
    }
    out[(size_t)li * 128 * 64 + idx] = __float2half(v);
}

__global__ __launch_bounds__(256) void prep_f16cvt(
    const float* __restrict__ w, _Float16* __restrict__ o, int n)
{
    const int i = blockIdx.x * 256 + threadIdx.x;
    if (i < n) o[i] = (_Float16)w[i];
}

// ---------------- MFMA gate precompute (R7-verified; padded-row addressing) ----------------
template<int MODE>
__global__ __launch_bounds__(256) void precomp_mfma(
    const void* in_, _Float16* xp,
    const _Float16* __restrict__ wihpad,  // [128][KP]
    const _Float16* __restrict__ w1pad,   // [48][64] (MODE 2 only)
    int nrows)
{
    __shared__ _Float16 s_v[4][1024];     // per-wave 2KB swizzled V tile [16][64]
    const int tid  = threadIdx.x;
    const int wid  = tid >> 6, lane = tid & 63;
    const int g    = lane >> 4, r = lane & 15;

    constexpr int KP  = (MODE == 0) ? 32 : 64;
    constexpr int NKS = KP / 32;

    half8 bw[8][NKS];
    #pragma unroll
    for (int t = 0; t < 8; ++t)
        #pragma unroll
        for (int ks = 0; ks < NKS; ++ks)
            bw[t][ks] = *reinterpret_cast<const half8*>(wihpad + (t * 16 + r) * KP + ks * 32 + g * 8);

    half8 b1f[3][2];
    char* myv = nullptr;
    if constexpr (MODE == 2) {
        #pragma unroll
        for (int t = 0; t < 3; ++t)
            #pragma unroll
            for (int ks = 0; ks < 2; ++ks)
                b1f[t][ks] = *reinterpret_cast<const half8*>(w1pad + (t * 16 + r) * 64 + ks * 32 + g * 8);
        myv = (char*)&s_v[wid][0];
        uint4 z; z.x = z.y = z.z = z.w = 0u;
        *reinterpret_cast<uint4*>(myv + lane * 32)      = z;
        *reinterpret_cast<uint4*>(myv + lane * 32 + 16) = z;
        wavesync();
        if (lane < 16)
            *reinterpret_cast<_Float16*>(myv + lane * 128 + (126 ^ ((lane & 7) << 4))) = (_Float16)1.f;
        wavesync();
    }

    const int w0     = blockIdx.x * 4 + wid;
    const int stride = gridDim.x * 64;

    for (int rb = w0 * 16; rb < nrows; rb += stride) {
        half8 a0, a1;
        if constexpr (MODE == 0) {
            const float* xr = (const float*)in_ + (size_t)(rb + r) * 20;
            if (g < 2) {
                const float4 v0 = *reinterpret_cast<const float4*>(xr + g * 8);
                const float4 v1 = *reinterpret_cast<const float4*>(xr + g * 8 + 4);
                a0[0]=(_Float16)v0.x; a0[1]=(_Float16)v0.y; a0[2]=(_Float16)v0.z; a0[3]=(_Float16)v0.w;
                a0[4]=(_Float16)v1.x; a0[5]=(_Float16)v1.y; a0[6]=(_Float16)v1.z; a0[7]=(_Float16)v1.w;
            } else if (g == 2) {
                const float4 v0 = *reinterpret_cast<const float4*>(xr + 16);
                a0[0]=(_Float16)v0.x; a0[1]=(_Float16)v0.y; a0[2]=(_Float16)v0.z; a0[3]=(_Float16)v0.w;
                a0[4]=(_Float16)0.f; a0[5]=(_Float16)0.f; a0[6]=(_Float16)0.f; a0[7]=(_Float16)0.f;
            } else {
                #pragma unroll
                for (int j = 0; j < 8; ++j) a0[j] = (_Float16)0.f;
                a0[7] = (_Float16)1.f;    // bias slot k=31
            }
        } else {
            const _Float16* hr = (const _Float16*)in_ + rowoff(rb + r);
            a0 = *reinterpret_cast<const half8*>(hr + g * 8);          // k 0..31
            if (g == 0) {
                a1 = *reinterpret_cast<const half8*>(hr + 32);         // k 32..39
            } else {
                #pragma unroll
                for (int j = 0; j < 8; ++j) a1[j] = (_Float16)0.f;
                if (g == 3) a1[7] = (_Float16)1.f;                     // bias slot k=63
            }
        }

        if constexpr (MODE == 2) {
            #pragma unroll
            for (int t = 0; t < 3; ++t) {
                f32x4 acc = {0.f, 0.f, 0.f, 0.f};
                acc = __builtin_amdgcn_mfma_f32_16x16x32_f16(a0, b1f[t][0], acc, 0, 0, 0);
                acc = __builtin_amdgcn_mfma_f32_16x16x32_f16(a1, b1f[t][1], acc, 0, 0, 0);
                const int n2 = (t * 16 + r) * 2;                       // byte col
                #pragma unroll
                for (int reg = 0; reg < 4; ++reg) {
                    const int m = g * 4 + reg;
                    float v = acc[reg];
                    v = v > 0.f ? v : 0.01f * v;
                    *reinterpret_cast<_Float16*>(myv + m * 128 + (n2 ^ ((m & 7) << 4))) = (_Float16)v;
                }
            }
            wavesync();
            const int sw = (r & 7) << 4;
            a0 = *reinterpret_cast<const half8*>(myv + r * 128 + ((g * 16) ^ sw));
            a1 = *reinterpret_cast<const half8*>(myv + r * 128 + ((64 + g * 16) ^ sw));
        }

        #pragma unroll
        for (int t = 0; t < 8; ++t) {
            f32x4 acc = {0.f, 0.f, 0.f, 0.f};
            acc = __builtin_amdgcn_mfma_f32_16x16x32_f16(a0, bw[t][0], acc, 0, 0, 0);
            if constexpr (NKS == 2)
                acc = __builtin_amdgcn_mfma_f32_16x16x32_f16(a1, bw[t][1], acc, 0, 0, 0);
            const int n = t * 16 + r;
            if (n < GATES) {
                #pragma unroll
                for (int reg = 0; reg < 4; ++reg) {
                    const int m = g * 4 + reg;
                    xp[rowoff(rb + m) + n] = (_Float16)acc[reg];
                }
            }
        }
    }
}

// ---------------- recurrence: 2 elements per wave, shared register weights ----------------
// Two independent serial chains interleave in one wave (elem1's dots fill elem0's
// transcendental/LDS stalls and vice versa). Weights SHARED: 40 dwords for both
// elements, LDS-staged -> registers, pinned by waves_per_eu(1,1) (512-VGPR budget
// -> zero allocator squeeze; kills the R8-R15 reload failure mode) + loop clobber.
// Grid = B/2 blocks (1 wave/SIMD) — R13 proved within-wave dual-chain ~ matches
// 2-wave round-robin even WITH per-step weight reloads; this removes the reloads.
__global__ __launch_bounds__(64)
__attribute__((amdgpu_waves_per_eu(1, 1)))
void gru_recE2(
    __half* __restrict__ xp,            // [CB, ROWSP, 120], h written into [t][0:40]
    const _Float16* __restrict__ whh16, // [120][40] f16
    const float* __restrict__ bhh)      // [120]
{
    __shared__ __align__(16) _Float16 s_w[GATES * HID];  // 9600 B staging
    __shared__ __align__(16) _Float16 s_h[2][64];

    const int lane = threadIdx.x;
    const int e0   = blockIdx.x * 2;

    for (int idx = lane; idx < (GATES * HID) / 8; idx += 64)
        reinterpret_cast<uint4*>(s_w)[idx] = reinterpret_cast<const uint4*>(whh16)[idx];

    const int gA = lane;
    const int gB = (lane < 40) ? (80 + lane) : ((lane < 56) ? (24 + lane) : lane);
    const float bhA = bhh[gA], bhB = bhh[gB];

    __half* xpb0 = xp + (size_t)e0 * ROWSP * GATES;
    __half* xpb1 = xpb0 + (size_t)ROWSP * GATES;

    float h0 = 0.f, h1 = 0.f;
    s_h[0][lane] = (_Float16)0.f;
    s_h[1][lane] = (_Float16)0.f;
    wavesync();   // staging + init complete

    // pull this lane's 2 weight rows from LDS into registers (40 dwords, SHARED)
    fp16x2 wA[20], wB[20];
    {
        const _Float16* wrA = s_w + gA * HID;
        const _Float16* wrB = s_w + gB * HID;
        #pragma unroll
        for (int k = 0; k < 5; ++k) {
            const half8 wa = *reinterpret_cast<const half8*>(wrA + k * 8);
            const half8 wb = *reinterpret_cast<const half8*>(wrB + k * 8);
            wA[4*k+0] = ext2<0>(wa); wB[4*k+0] = ext2<0>(wb);
            wA[4*k+1] = ext2<1>(wa); wB[4*k+1] = ext2<1>(wb);
            wA[4*k+2] = ext2<2>(wa); wB[4*k+2] = ext2<2>(wb);
            wA[4*k+3] = ext2<3>(wa); wB[4*k+3] = ext2<3>(wb);
        }
    }
    wavesync();

    // 3-deep prefetch per element, pointer-bumped; padded rows -> unconditional
    __half a00 = xpb0[gA],             c00 = xpb0[gB];
    __half a01 = xpb0[GATES + gA],     c01 = xpb0[GATES + gB];
    __half a02 = xpb0[2 * GATES + gA], c02 = xpb0[2 * GATES + gB];
    __half a10 = xpb1[gA],             c10 = xpb1[gB];
    __half a11 = xpb1[GATES + gA],     c11 = xpb1[GATES + gB];
    __half a12 = xpb1[2 * GATES + gA], c12 = xpb1[2 * GATES + gB];
    const __half* pfA0 = xpb0 + 3 * GATES + gA;
    const __half* pfB0 = xpb0 + 3 * GATES + gB;
    const __half* pfA1 = xpb1 + 3 * GATES + gA;
    const __half* pfB1 = xpb1 + 3 * GATES + gB;
    __half* pst0 = xpb0 + lane;
    __half* pst1 = xpb1 + lane;

    #pragma unroll 2
    for (int t = 0; t < T_STEPS; ++t) {
        const __half a03 = *pfA0;  pfA0 += GATES;
        const __half c03 = *pfB0;  pfB0 += GATES;
        const __half a13 = *pfA1;  pfA1 += GATES;
        const __half c13 = *pfB1;  pfB1 += GATES;

        const half8 p00 = *reinterpret_cast<const half8*>(&s_h[0][0]);
        const half8 p01 = *reinterpret_cast<const half8*>(&s_h[0][8]);
        const half8 p02 = *reinterpret_cast<const half8*>(&s_h[0][16]);
        const half8 p03 = *reinterpret_cast<const half8*>(&s_h[0][24]);
        const half8 p04 = *reinterpret_cast<const half8*>(&s_h[0][32]);
        const half8 p10 = *reinterpret_cast<const half8*>(&s_h[1][0]);
        const half8 p11 = *reinterpret_cast<const half8*>(&s_h[1][8]);
        const half8 p12 = *reinterpret_cast<const half8*>(&s_h[1][16]);
        const half8 p13 = *reinterpret_cast<const half8*>(&s_h[1][24]);
        const half8 p14 = *reinterpret_cast<const half8*>(&s_h[1][32]);

        // element 0 dots (8 chains) interleaved with element 1 dots (8 chains)
        float A0=0.f,A1=0.f,A2=0.f,A3=0.f, B0=0.f,B1=0.f,B2=0.f,B3=0.f;
        float D0=0.f,D1=0.f,D2=0.f,D3=0.f, E0=0.f,E1=0.f,E2=0.f,E3=0.f;
        #define STEP(P0, Q0, KBASE) \
            A0 = fdot2(ext2<0>(P0), wA[KBASE+0], A0); B0 = fdot2(ext2<0>(P0), wB[KBASE+0], B0); \
            D0 = fdot2(ext2<0>(Q0), wA[KBASE+0], D0); E0 = fdot2(ext2<0>(Q0), wB[KBASE+0], E0); \
            A1 = fdot2(ext2<1>(P0), wA[KBASE+1], A1); B1 = fdot2(ext2<1>(P0), wB[KBASE+1], B1); \
            D1 = fdot2(ext2<1>(Q0), wA[KBASE+1], D1); E1 = fdot2(ext2<1>(Q0), wB[KBASE+1], E1); \
            A2 = fdot2(ext2<2>(P0), wA[KBASE+2], A2); B2 = fdot2(ext2<2>(P0), wB[KBASE+2], B2); \
            D2 = fdot2(ext2<2>(Q0), wA[KBASE+2], D2); E2 = fdot2(ext2<2>(Q0), wB[KBASE+2], E2); \
            A3 = fdot2(ext2<3>(P0), wA[KBASE+3], A3); B3 = fdot2(ext2<3>(P0), wB[KBASE+3], B3); \
            D3 = fdot2(ext2<3>(Q0), wA[KBASE+3], D3); E3 = fdot2(ext2<3>(Q0), wB[KBASE+3], E3);
        STEP(p00, p10,  0)
        STEP(p01, p11,  4)
        STEP(p02, p12,  8)
        STEP(p03, p13, 12)
        STEP(p04, p14, 16)
        #undef STEP

        const float shA0 = bhA + ((A0 + A2) + (A1 + A3));
        const float shB0 = bhB + ((B0 + B2) + (B1 + B3));
        const float shA1 = bhA + ((D0 + D2) + (D1 + D3));
        const float shB1 = bhB + ((E0 + E2) + (E1 + E3));
        const float xA0 = __half2float(a00), xB0 = __half2float(c00);
        const float xA1 = __half2float(a10), xB1 = __half2float(c10);
        const float sumA0 = xA0 + shA0, sumB0 = xB0 + shB0;
        const float sumA1 = xA1 + shA1, sumB1 = xB1 + shB1;
        // z_l: lane 40+l (sumA) for l<24, lane 16+l (sumB) for l>=24. All lanes execute.
        const float zA0 = bperm(40 + lane, sumA0), zB0 = bperm(16 + lane, sumB0);
        const float zA1 = bperm(40 + lane, sumA1), zB1 = bperm(16 + lane, sumB1);

        // branch-free activations; lanes>=40 garbage -> unread s_h slots only
        {
            const float rr  = sigm(sumA0);
            const float z   = sigm((lane < 24) ? zA0 : zB0);
            const float pre = xB0 + rr * shB0;
            const float ex  = __expf(-2.f * pre);
            const float nn  = (1.f - ex) / (1.f + ex);
            h0 = (1.f - z) * nn + z * h0;
            s_h[0][lane] = (_Float16)h0;
        }
        {
            const float rr  = sigm(sumA1);
            const float z   = sigm((lane < 24) ? zA1 : zB1);
            const float pre = xB1 + rr * shB1;
            const float ex  = __expf(-2.f * pre);
            const float nn  = (1.f - ex) / (1.f + ex);
            h1 = (1.f - z) * nn + z * h1;
            s_h[1][lane] = (_Float16)h1;
        }
        if (lane < HID) {
            *pst0 = __float2half(h0);
            *pst1 = __float2half(h1);
        }
        pst0 += GATES;  pst1 += GATES;

        a00 = a01; c00 = c01; a01 = a02; c01 = c02; a02 = a03; c02 = c03;
        a10 = a11; c10 = c11; a11 = a12; c11 = c12; a12 = a13; c12 = c13;
        wavesync();   // s_h ordered; clobber keeps weights resident
    }
}

// ---------------- head ----------------
__global__ __launch_bounds__(256) void final_head(
    const __half* __restrict__ xpbuf,  // padded buffer base
    float* __restrict__ outp,          // [CB]
    const float* __restrict__ w1, const float* __restrict__ b1,
    const float* __restrict__ wl, const float* __restrict__ bl, int n)
{
    __shared__ float s_w1[HID][HID + 1];
    __shared__ float s_b1[HID];
    __shared__ float s_wl[HID];
    for (int i = threadIdx.x; i < HID * HID; i += 256) s_w1[i / HID][i % HID] = w1[i];
    if (threadIdx.x < HID) { s_b1[threadIdx.x] = b1[threadIdx.x]; s_wl[threadIdx.x] = wl[threadIdx.x]; }
    __syncthreads();
    const int e = blockIdx.x * 256 + threadIdx.x;
    if (e >= n) return;

    const __half* hbase = xpbuf + ((size_t)e * ROWSP + (T_STEPS - 1)) * GATES;
    alignas(16) __half hx[HID];
    const uint4* hr = reinterpret_cast<const uint4*>(hbase);
    #pragma unroll
    for (int q = 0; q < HID / 8; ++q) reinterpret_cast<uint4*>(hx)[q] = hr[q];
    float h[HID];
    #pragma unroll
    for (int k = 0; k < HID; ++k) h[k] = __half2float(hx[k]);

    float acc = bl[0];
    #pragma unroll
    for (int u = 0; u < HID; ++u) {
        float a = s_b1[u];
        #pragma unroll
        for (int d = 0; d < HID; ++d) a += s_w1[u][d] * h[d];
        a = a > 0.f ? a : 0.01f * a;
        acc += a * s_wl[u];
    }
    outp[e] = 1.f / (1.f + __expf(-acc));
}

extern "C" void kernel_launch(void* const* d_in, const int* in_sizes, int n_in,
                              void* d_out, int out_size, void* d_ws, size_t ws_size,
                              hipStream_t stream)
{
    const float* x      = (const float*)d_in[0];
    const float* g0_wih = (const float*)d_in[1];
    const float* g0_whh = (const float*)d_in[2];
    const float* g0_bih = (const float*)d_in[3];
    const float* g0_bhh = (const float*)d_in[4];
    const float* g_wih  = (const float*)d_in[5];   // [4,120,40]
    const float* g_whh  = (const float*)d_in[6];   // [4,120,40]
    const float* g_bih  = (const float*)d_in[7];   // [4,120]
    const float* g_bhh  = (const float*)d_in[8];   // [4,120]
    const float* mlp_w1 = (const float*)d_in[9];   // [4,40,40]
    const float* mlp_b1 = (const float*)d_in[10];  // [4,40]
    const float* mlp_w2 = (const float*)d_in[11];  // [3,40,40]
    const float* mlp_b2 = (const float*)d_in[12];  // [3,40]
    const float* w_last = (const float*)d_in[13];  // [1,40]
    const float* b_last = (const float*)d_in[14];  // [1]

    const int B = in_sizes[0] / (T_STEPS * 20);
    float* out = (float*)d_out;

    // ws (halfs): [w1pad 3*3072][effpad 3*8192][g0pad 4096][g1pad 8192][whh16 5*4800] then xp
    __half* wsz    = (__half*)d_ws;
    __half* w1pad  = wsz;                       // 9216
    __half* effpad = wsz + 3 * 3072;            // 24576
    __half* g0pad  = wsz + 9216 + 3 * 8192;     // 4096
    __half* g1pad  = g0pad + 4096;              // 8192
    _Float16* whh16 = (_Float16*)(wsz + 46080); // 24000
    _Float16* xpbuf = (_Float16*)(wsz + 70080); // 140160 B of weights, 16B aligned
    const size_t ws_rem = ws_size - 70080 * sizeof(__half);

    for (int li = 0; li < 3; ++li)
        prep_pad<<<dim3(12), dim3(256), 0, stream>>>(
            mlp_w1 + li * 1600, mlp_b1 + li * 40, w1pad + li * 3072, 40, 40, 64);
    prep_pad<<<dim3(16), dim3(256), 0, stream>>>(g0_wih, g0_bih, g0pad, 120, 20, 32);
    prep_pad<<<dim3(32), dim3(256), 0, stream>>>(g_wih, g_bih, g1pad, 120, 40, 64);
    prep_eff<<<dim3(32, 3), dim3(256), 0, stream>>>(g_wih, g_bih, mlp_w2, mlp_b2, effpad);
    prep_f16cvt<<<dim3(19), dim3(256), 0, stream>>>(g0_whh, whh16, 4800);
    prep_f16cvt<<<dim3(75), dim3(256), 0, stream>>>(g_whh, whh16 + 4800, 19200);

    const size_t per_e = (size_t)ROWSP * GATES * sizeof(__half);  // padded element footprint
    int CB = B;
    while ((size_t)CB * per_e > ws_rem && CB > 64) CB >>= 1;

    for (int c = 0; c < B; c += CB) {
        const int  nrows = CB * T_STEPS;
        const dim3 pgrd(nrows / 512), pblk(256);
        const dim3 rgrd(CB / 2), rblk(64);
        const float* xc = x + (size_t)c * T_STEPS * 20;

        precomp_mfma<0><<<pgrd, pblk, 0, stream>>>(
            xc, xpbuf, (const _Float16*)g0pad, nullptr, nrows);
        gru_recE2<<<rgrd, rblk, 0, stream>>>((__half*)xpbuf, whh16, g0_bhh);

        precomp_mfma<1><<<pgrd, pblk, 0, stream>>>(
            xpbuf, xpbuf, (const _Float16*)g1pad, nullptr, nrows);
        gru_recE2<<<rgrd, rblk, 0, stream>>>((__half*)xpbuf, whh16 + 4800, g_bhh + 0 * 120);

        for (int li = 0; li < 3; ++li) {
            precomp_mfma<2><<<pgrd, pblk, 0, stream>>>(
                xpbuf, xpbuf, (const _Float16*)(effpad + li * 8192),
                (const _Float16*)(w1pad + li * 3072), nrows);
            gru_recE2<<<rgrd, rblk, 0, stream>>>(
                (__half*)xpbuf, whh16 + 4800 + (li + 1) * 4800, g_bhh + (li + 1) * 120);
        }

        final_head<<<dim3((CB + 255) / 256), dim3(256), 0, stream>>>(
            (const __half*)xpbuf, out + c,
            mlp_w1 + 3 * 1600, mlp_b1 + 3 * 40, w_last, b_last, CB);
    }
}

// Round 23
// 1671.021 us; speedup vs baseline: 1.2303x; 1.2303x over previous
//
#include <hip/hip_runtime.h>
#include <hip/hip_fp16.h>
#include <cstdint>
#include <cstddef>

#define T_STEPS 512
#define ROWSP   516          // padded rows per element (3-deep unconditional prefetch)
#define HID 40
#define GATES 120

typedef _Float16 half8 __attribute__((ext_vector_type(8)));
typedef _Float16 fp16x2 __attribute__((ext_vector_type(2)));
typedef float f32x4 __attribute__((ext_vector_type(4)));

__device__ __forceinline__ void wavesync() { asm volatile("s_waitcnt lgkmcnt(0)" ::: "memory"); }
__device__ __forceinline__ float bperm(int srclane, float v) {
    return __int_as_float(__builtin_amdgcn_ds_bpermute(srclane << 2, __float_as_int(v)));
}
__device__ __forceinline__ float sigm(float x) { return 1.f / (1.f + __expf(-x)); }

template<int J>
__device__ __forceinline__ fp16x2 ext2(half8 v) {
    return __builtin_shufflevector(v, v, 2 * J, 2 * J + 1);
}

#if __has_builtin(__builtin_amdgcn_fdot2)
__device__ __forceinline__ float fdot2(fp16x2 a, fp16x2 b, float c) {
    return __builtin_amdgcn_fdot2(a, b, c, false);
}
#else
__device__ __forceinline__ float fdot2(fp16x2 a, fp16x2 b, float c) {
    return c + (float)a[0] * (float)b[0] + (float)a[1] * (float)b[1];
}
#endif

// padded-row byte mapping: row i (linear e*512+t) lives at (e*516+t)*GATES
__device__ __forceinline__ size_t rowoff(int row) {
    return ((size_t)(row >> 9) * ROWSP + (row & 511)) * GATES;
}

// ---------------- weight prep (run once, tiny) ----------------
__global__ __launch_bounds__(256) void prep_pad(
    const float* __restrict__ w, const float* __restrict__ b,
    __half* __restrict__ out, int N, int K, int KPAD)
{
    const int idx = blockIdx.x * 256 + threadIdx.x;
    const int n = idx / KPAD, k = idx - n * KPAD;
    float v = 0.f;
    if (n < N) {
        if (k < K) v = w[n * K + k];
        else if (k == KPAD - 1) v = b[n];
    }
    out[idx] = __float2half(v);
}

__global__ __launch_bounds__(256) void prep_eff(
    const float* __restrict__ g_wih, const float* __restrict__ g_bih,
    const float* __restrict__ w2, const float* __restrict__ b2,
    __half* __restrict__ out)
{
    const int li  = blockIdx.y;
    const int idx = blockIdx.x * 256 + threadIdx.x;   // over 128*64
    const int n = idx >> 6, k = idx & 63;
    float v = 0.f;
    if (n < GATES) {
        const float* wrow = g_wih + ((size_t)(li + 1) * GATES + n) * HID;
        if (k < HID) {
            for (int j = 0; j < HID; ++j) v += wrow[j] * w2[((size_t)li * HID + j) * HID + k];
        } else if (k == 63) {
            v = g_bih[(size_t)(li + 1) * GATES + n];
            for (int j = 0; j < HID; ++j) v += wrow[j] * b2[(size_t)li * HID + j];
        }
    }
    out[(size_t)li * 128 * 64 + idx] = __float2half(v);
}

__global__ __launch_bounds__(256) void prep_f16cvt(
    const float* __restrict__ w, _Float16* __restrict__ o, int n)
{
    const int i = blockIdx.x * 256 + threadIdx.x;
    if (i < n) o[i] = (_Float16)w[i];
}

// ---------------- MFMA gate precompute (R7-verified; padded-row addressing) ----------------
template<int MODE>
__global__ __launch_bounds__(256) void precomp_mfma(
    const void* in_, _Float16* xp,
    const _Float16* __restrict__ wihpad,  // [128][KP]
    const _Float16* __restrict__ w1pad,   // [48][64] (MODE 2 only)
    int nrows)
{
    __shared__ _Float16 s_v[4][1024];     // per-wave 2KB swizzled V tile [16][64]
    const int tid  = threadIdx.x;
    const int wid  = tid >> 6, lane = tid & 63;
    const int g    = lane >> 4, r = lane & 15;

    constexpr int KP  = (MODE == 0) ? 32 : 64;
    constexpr int NKS = KP / 32;

    half8 bw[8][NKS];
    #pragma unroll
    for (int t = 0; t < 8; ++t)
        #pragma unroll
        for (int ks = 0; ks < NKS; ++ks)
            bw[t][ks] = *reinterpret_cast<const half8*>(wihpad + (t * 16 + r) * KP + ks * 32 + g * 8);

    half8 b1f[3][2];
    char* myv = nullptr;
    if constexpr (MODE == 2) {
        #pragma unroll
        for (int t = 0; t < 3; ++t)
            #pragma unroll
            for (int ks = 0; ks < 2; ++ks)
                b1f[t][ks] = *reinterpret_cast<const half8*>(w1pad + (t * 16 + r) * 64 + ks * 32 + g * 8);
        myv = (char*)&s_v[wid][0];
        uint4 z; z.x = z.y = z.z = z.w = 0u;
        *reinterpret_cast<uint4*>(myv + lane * 32)      = z;
        *reinterpret_cast<uint4*>(myv + lane * 32 + 16) = z;
        wavesync();
        if (lane < 16)
            *reinterpret_cast<_Float16*>(myv + lane * 128 + (126 ^ ((lane & 7) << 4))) = (_Float16)1.f;
        wavesync();
    }

    const int w0     = blockIdx.x * 4 + wid;
    const int stride = gridDim.x * 64;

    for (int rb = w0 * 16; rb < nrows; rb += stride) {
        half8 a0, a1;
        if constexpr (MODE == 0) {
            const float* xr = (const float*)in_ + (size_t)(rb + r) * 20;
            if (g < 2) {
                const float4 v0 = *reinterpret_cast<const float4*>(xr + g * 8);
                const float4 v1 = *reinterpret_cast<const float4*>(xr + g * 8 + 4);
                a0[0]=(_Float16)v0.x; a0[1]=(_Float16)v0.y; a0[2]=(_Float16)v0.z; a0[3]=(_Float16)v0.w;
                a0[4]=(_Float16)v1.x; a0[5]=(_Float16)v1.y; a0[6]=(_Float16)v1.z; a0[7]=(_Float16)v1.w;
            } else if (g == 2) {
                const float4 v0 = *reinterpret_cast<const float4*>(xr + 16);
                a0[0]=(_Float16)v0.x; a0[1]=(_Float16)v0.y; a0[2]=(_Float16)v0.z; a0[3]=(_Float16)v0.w;
                a0[4]=(_Float16)0.f; a0[5]=(_Float16)0.f; a0[6]=(_Float16)0.f; a0[7]=(_Float16)0.f;
            } else {
                #pragma unroll
                for (int j = 0; j < 8; ++j) a0[j] = (_Float16)0.f;
                a0[7] = (_Float16)1.f;    // bias slot k=31
            }
        } else {
            const _Float16* hr = (const _Float16*)in_ + rowoff(rb + r);
            a0 = *reinterpret_cast<const half8*>(hr + g * 8);          // k 0..31
            if (g == 0) {
                a1 = *reinterpret_cast<const half8*>(hr + 32);         // k 32..39
            } else {
                #pragma unroll
                for (int j = 0; j < 8; ++j) a1[j] = (_Float16)0.f;
                if (g == 3) a1[7] = (_Float16)1.f;                     // bias slot k=63
            }
        }

        if constexpr (MODE == 2) {
            #pragma unroll
            for (int t = 0; t < 3; ++t) {
                f32x4 acc = {0.f, 0.f, 0.f, 0.f};
                acc = __builtin_amdgcn_mfma_f32_16x16x32_f16(a0, b1f[t][0], acc, 0, 0, 0);
                acc = __builtin_amdgcn_mfma_f32_16x16x32_f16(a1, b1f[t][1], acc, 0, 0, 0);
                const int n2 = (t * 16 + r) * 2;                       // byte col
                #pragma unroll
                for (int reg = 0; reg < 4; ++reg) {
                    const int m = g * 4 + reg;
                    float v = acc[reg];
                    v = v > 0.f ? v : 0.01f * v;
                    *reinterpret_cast<_Float16*>(myv + m * 128 + (n2 ^ ((m & 7) << 4))) = (_Float16)v;
                }
            }
            wavesync();
            const int sw = (r & 7) << 4;
            a0 = *reinterpret_cast<const half8*>(myv + r * 128 + ((g * 16) ^ sw));
            a1 = *reinterpret_cast<const half8*>(myv + r * 128 + ((64 + g * 16) ^ sw));
        }

        #pragma unroll
        for (int t = 0; t < 8; ++t) {
            f32x4 acc = {0.f, 0.f, 0.f, 0.f};
            acc = __builtin_amdgcn_mfma_f32_16x16x32_f16(a0, bw[t][0], acc, 0, 0, 0);
            if constexpr (NKS == 2)
                acc = __builtin_amdgcn_mfma_f32_16x16x32_f16(a1, bw[t][1], acc, 0, 0, 0);
            const int n = t * 16 + r;
            if (n < GATES) {
                #pragma unroll
                for (int reg = 0; reg < 4; ++reg) {
                    const int m = g * 4 + reg;
                    xp[rowoff(rb + m) + n] = (_Float16)acc[reg];
                }
            }
        }
    }
}

// ---------------- recurrence: R16 champion (LDS-staged register weights) ----------------
// waves_per_eu(2,2) tells the backend the true occupancy (grid=2048 single-wave
// blocks -> 2 waves/SIMD max), unlocking the VGPR budget so the 40 weight dwords
// stay resident (VGPR_Count 52->88, 360->272us). Weights come from LDS written
// in-kernel behind a memory clobber -> not provably-invariant -> no remat reloads.
__global__ __launch_bounds__(64)
__attribute__((amdgpu_waves_per_eu(2, 2)))
void gru_recR(
    __half* __restrict__ xp,            // [CB, ROWSP, 120], h written into [t][0:40]
    const _Float16* __restrict__ whh16, // [120][40] f16
    const float* __restrict__ bhh)      // [120]
{
    __shared__ __align__(16) _Float16 s_w[GATES * HID];  // 9600 B staging
    __shared__ __align__(16) _Float16 s_h[64];

    const int lane = threadIdx.x;
    const int e    = blockIdx.x;

    for (int idx = lane; idx < (GATES * HID) / 8; idx += 64)
        reinterpret_cast<uint4*>(s_w)[idx] = reinterpret_cast<const uint4*>(whh16)[idx];

    const int gA = lane;
    const int gB = (lane < 40) ? (80 + lane) : ((lane < 56) ? (24 + lane) : lane);
    const float bhA = bhh[gA], bhB = bhh[gB];

    __half* xpb = xp + (size_t)e * ROWSP * GATES;

    float hreg = 0.f;
    s_h[lane] = (_Float16)0.f;
    wavesync();   // staging + init complete

    // pull this lane's 2 weight rows from LDS into registers (40 dwords)
    fp16x2 wA[20], wB[20];
    {
        const _Float16* wrA = s_w + gA * HID;
        const _Float16* wrB = s_w + gB * HID;
        #pragma unroll
        for (int k = 0; k < 5; ++k) {
            const half8 wa = *reinterpret_cast<const half8*>(wrA + k * 8);
            const half8 wb = *reinterpret_cast<const half8*>(wrB + k * 8);
            wA[4*k+0] = ext2<0>(wa); wB[4*k+0] = ext2<0>(wb);
            wA[4*k+1] = ext2<1>(wa); wB[4*k+1] = ext2<1>(wb);
            wA[4*k+2] = ext2<2>(wa); wB[4*k+2] = ext2<2>(wb);
            wA[4*k+3] = ext2<3>(wa); wB[4*k+3] = ext2<3>(wb);
        }
    }
    wavesync();

    // 3-deep prefetch, pointer-bumped; padded rows make it unconditional
    __half a0 = xpb[gA],             c0 = xpb[gB];
    __half a1 = xpb[GATES + gA],     c1 = xpb[GATES + gB];
    __half a2 = xpb[2 * GATES + gA], c2 = xpb[2 * GATES + gB];
    const __half* pfA = xpb + 3 * GATES + gA;
    const __half* pfB = xpb + 3 * GATES + gB;
    __half*       pst = xpb + lane;

    #pragma unroll 4
    for (int t = 0; t < T_STEPS; ++t) {
        const __half a3 = *pfA;  pfA += GATES;
        const __half c3 = *pfB;  pfB += GATES;

        const half8 p0 = *reinterpret_cast<const half8*>(&s_h[0]);
        const half8 p1 = *reinterpret_cast<const half8*>(&s_h[8]);
        const half8 p2 = *reinterpret_cast<const half8*>(&s_h[16]);
        const half8 p3 = *reinterpret_cast<const half8*>(&s_h[24]);
        const half8 p4 = *reinterpret_cast<const half8*>(&s_h[32]);

        float A0 = 0.f, A1 = 0.f, A2 = 0.f, A3 = 0.f;
        float B0 = 0.f, B1 = 0.f, B2 = 0.f, B3 = 0.f;
        A0 = fdot2(ext2<0>(p0), wA[ 0], A0); B0 = fdot2(ext2<0>(p0), wB[ 0], B0);
        A1 = fdot2(ext2<1>(p0), wA[ 1], A1); B1 = fdot2(ext2<1>(p0), wB[ 1], B1);
        A2 = fdot2(ext2<2>(p0), wA[ 2], A2); B2 = fdot2(ext2<2>(p0), wB[ 2], B2);
        A3 = fdot2(ext2<3>(p0), wA[ 3], A3); B3 = fdot2(ext2<3>(p0), wB[ 3], B3);
        A0 = fdot2(ext2<0>(p1), wA[ 4], A0); B0 = fdot2(ext2<0>(p1), wB[ 4], B0);
        A1 = fdot2(ext2<1>(p1), wA[ 5], A1); B1 = fdot2(ext2<1>(p1), wB[ 5], B1);
        A2 = fdot2(ext2<2>(p1), wA[ 6], A2); B2 = fdot2(ext2<2>(p1), wB[ 6], B2);
        A3 = fdot2(ext2<3>(p1), wA[ 7], A3); B3 = fdot2(ext2<3>(p1), wB[ 7], B3);
        A0 = fdot2(ext2<0>(p2), wA[ 8], A0); B0 = fdot2(ext2<0>(p2), wB[ 8], B0);
        A1 = fdot2(ext2<1>(p2), wA[ 9], A1); B1 = fdot2(ext2<1>(p2), wB[ 9], B1);
        A2 = fdot2(ext2<2>(p2), wA[10], A2); B2 = fdot2(ext2<2>(p2), wB[10], B2);
        A3 = fdot2(ext2<3>(p2), wA[11], A3); B3 = fdot2(ext2<3>(p2), wB[11], B3);
        A0 = fdot2(ext2<0>(p3), wA[12], A0); B0 = fdot2(ext2<0>(p3), wB[12], B0);
        A1 = fdot2(ext2<1>(p3), wA[13], A1); B1 = fdot2(ext2<1>(p3), wB[13], B1);
        A2 = fdot2(ext2<2>(p3), wA[14], A2); B2 = fdot2(ext2<2>(p3), wB[14], B2);
        A3 = fdot2(ext2<3>(p3), wA[15], A3); B3 = fdot2(ext2<3>(p3), wB[15], B3);
        A0 = fdot2(ext2<0>(p4), wA[16], A0); B0 = fdot2(ext2<0>(p4), wB[16], B0);
        A1 = fdot2(ext2<1>(p4), wA[17], A1); B1 = fdot2(ext2<1>(p4), wB[17], B1);
        A2 = fdot2(ext2<2>(p4), wA[18], A2); B2 = fdot2(ext2<2>(p4), wB[18], B2);
        A3 = fdot2(ext2<3>(p4), wA[19], A3); B3 = fdot2(ext2<3>(p4), wB[19], B3);

        const float shA = bhA + ((A0 + A2) + (A1 + A3));
        const float shB = bhB + ((B0 + B2) + (B1 + B3));
        const float xA  = __half2float(a0);
        const float xB  = __half2float(c0);
        const float sumA = xA + shA;
        const float sumB = xB + shB;
        // z_l: lane 40+l (sumA) for l<24, lane 16+l (sumB) for l>=24. All lanes execute.
        const float zA = bperm(40 + lane, sumA);
        const float zB = bperm(16 + lane, sumB);

        if (lane < HID) {
            const float rr  = sigm(sumA);
            const float z   = sigm((lane < 24) ? zA : zB);
            const float pre = xB + rr * shB;          // x_n + r*h_n (biases included)
            const float ex  = __expf(-2.f * pre);
            const float nn  = (1.f - ex) / (1.f + ex);
            hreg = (1.f - z) * nn + z * hreg;
            s_h[lane] = (_Float16)hreg;
            *pst = __float2half(hreg);
        }
        pst += GATES;
        a0 = a1; c0 = c1; a1 = a2; c1 = c2; a2 = a3; c2 = c3;
        wavesync();   // s_h ordered for next step; clobber pins weights in regs
    }
}

// ---------------- head ----------------
__global__ __launch_bounds__(256) void final_head(
    const __half* __restrict__ xpbuf,  // padded buffer base
    float* __restrict__ outp,          // [CB]
    const float* __restrict__ w1, const float* __restrict__ b1,
    const float* __restrict__ wl, const float* __restrict__ bl, int n)
{
    __shared__ float s_w1[HID][HID + 1];
    __shared__ float s_b1[HID];
    __shared__ float s_wl[HID];
    for (int i = threadIdx.x; i < HID * HID; i += 256) s_w1[i / HID][i % HID] = w1[i];
    if (threadIdx.x < HID) { s_b1[threadIdx.x] = b1[threadIdx.x]; s_wl[threadIdx.x] = wl[threadIdx.x]; }
    __syncthreads();
    const int e = blockIdx.x * 256 + threadIdx.x;
    if (e >= n) return;

    const __half* hbase = xpbuf + ((size_t)e * ROWSP + (T_STEPS - 1)) * GATES;
    alignas(16) __half hx[HID];
    const uint4* hr = reinterpret_cast<const uint4*>(hbase);
    #pragma unroll
    for (int q = 0; q < HID / 8; ++q) reinterpret_cast<uint4*>(hx)[q] = hr[q];
    float h[HID];
    #pragma unroll
    for (int k = 0; k < HID; ++k) h[k] = __half2float(hx[k]);

    float acc = bl[0];
    #pragma unroll
    for (int u = 0; u < HID; ++u) {
        float a = s_b1[u];
        #pragma unroll
        for (int d = 0; d < HID; ++d) a += s_w1[u][d] * h[d];
        a = a > 0.f ? a : 0.01f * a;
        acc += a * s_wl[u];
    }
    outp[e] = 1.f / (1.f + __expf(-acc));
}

extern "C" void kernel_launch(void* const* d_in, const int* in_sizes, int n_in,
                              void* d_out, int out_size, void* d_ws, size_t ws_size,
                              hipStream_t stream)
{
    const float* x      = (const float*)d_in[0];
    const float* g0_wih = (const float*)d_in[1];
    const float* g0_whh = (const float*)d_in[2];
    const float* g0_bih = (const float*)d_in[3];
    const float* g0_bhh = (const float*)d_in[4];
    const float* g_wih  = (const float*)d_in[5];   // [4,120,40]
    const float* g_whh  = (const float*)d_in[6];   // [4,120,40]
    const float* g_bih  = (const float*)d_in[7];   // [4,120]
    const float* g_bhh  = (const float*)d_in[8];   // [4,120]
    const float* mlp_w1 = (const float*)d_in[9];   // [4,40,40]
    const float* mlp_b1 = (const float*)d_in[10];  // [4,40]
    const float* mlp_w2 = (const float*)d_in[11];  // [3,40,40]
    const float* mlp_b2 = (const float*)d_in[12];  // [3,40]
    const float* w_last = (const float*)d_in[13];  // [1,40]
    const float* b_last = (const float*)d_in[14];  // [1]

    const int B = in_sizes[0] / (T_STEPS * 20);
    float* out = (float*)d_out;

    // ws (halfs): [w1pad 3*3072][effpad 3*8192][g0pad 4096][g1pad 8192][whh16 5*4800] then xp
    __half* wsz    = (__half*)d_ws;
    __half* w1pad  = wsz;                       // 9216
    __half* effpad = wsz + 3 * 3072;            // 24576
    __half* g0pad  = wsz + 9216 + 3 * 8192;     // 4096
    __half* g1pad  = g0pad + 4096;              // 8192
    _Float16* whh16 = (_Float16*)(wsz + 46080); // 24000
    _Float16* xpbuf = (_Float16*)(wsz + 70080); // 140160 B of weights, 16B aligned
    const size_t ws_rem = ws_size - 70080 * sizeof(__half);

    for (int li = 0; li < 3; ++li)
        prep_pad<<<dim3(12), dim3(256), 0, stream>>>(
            mlp_w1 + li * 1600, mlp_b1 + li * 40, w1pad + li * 3072, 40, 40, 64);
    prep_pad<<<dim3(16), dim3(256), 0, stream>>>(g0_wih, g0_bih, g0pad, 120, 20, 32);
    prep_pad<<<dim3(32), dim3(256), 0, stream>>>(g_wih, g_bih, g1pad, 120, 40, 64);
    prep_eff<<<dim3(32, 3), dim3(256), 0, stream>>>(g_wih, g_bih, mlp_w2, mlp_b2, effpad);
    prep_f16cvt<<<dim3(19), dim3(256), 0, stream>>>(g0_whh, whh16, 4800);
    prep_f16cvt<<<dim3(75), dim3(256), 0, stream>>>(g_whh, whh16 + 4800, 19200);

    const size_t per_e = (size_t)ROWSP * GATES * sizeof(__half);  // padded element footprint
    int CB = B;
    while ((size_t)CB * per_e > ws_rem && CB > 64) CB >>= 1;

    for (int c = 0; c < B; c += CB) {
        const int  nrows = CB * T_STEPS;
        const dim3 pgrd(nrows / 512), pblk(256);
        const dim3 rgrd(CB), rblk(64);
        const float* xc = x + (size_t)c * T_STEPS * 20;

        precomp_mfma<0><<<pgrd, pblk, 0, stream>>>(
            xc, xpbuf, (const _Float16*)g0pad, nullptr, nrows);
        gru_recR<<<rgrd, rblk, 0, stream>>>((__half*)xpbuf, whh16, g0_bhh);

        precomp_mfma<1><<<pgrd, pblk, 0, stream>>>(
            xpbuf, xpbuf, (const _Float16*)g1pad, nullptr, nrows);
        gru_recR<<<rgrd, rblk, 0, stream>>>((__half*)xpbuf, whh16 + 4800, g_bhh + 0 * 120);

        for (int li = 0; li < 3; ++li) {
            precomp_mfma<2><<<pgrd, pblk, 0, stream>>>(
                xpbuf, xpbuf, (const _Float16*)(effpad + li * 8192),
                (const _Float16*)(w1pad + li * 3072), nrows);
            gru_recR<<<rgrd, rblk, 0, stream>>>(
                (__half*)xpbuf, whh16 + 4800 + (li + 1) * 4800, g_bhh + (li + 1) * 120);
        }

        final_head<<<dim3((CB + 255) / 256), dim3(256), 0, stream>>>(
            (const __half*)xpbuf, out + c,
            mlp_w1 + 3 * 1600, mlp_b1 + 3 * 40, w_last, b_last, CB);
    }
}